// Round 1
// baseline (219.605 us; speedup 1.0000x reference)
//
#include <hip/hip_runtime.h>
#include <math.h>

// ---------------------------------------------------------------------------
// H=W=512, CELL=8, P=16, NGH=32; 4096 patches of 16x16, one block per patch.
// conv1 3x3 1->40 fp32 VALU; conv2 3x3 40->40 bf16 MFMA; dense1 from acc regs.
//
// R7 post-mortem: 2.4 GB/dispatch of L2 reads (B-frags re-read by all 8
// waves; d1w2 288 KB re-read by all 4096 blocks) ~= 70 us at L2 BW plus
// exposed latency -> both pipes <26% busy. R8:
//  - B-weights staged to LDS once per block (flat 36.9 KB uint4 copy from a
//    prep-side image already in LDS layout); MFMA loop is pure LDS+MFMA.
//  - dense1 weights bf16 [pixel][co:48][k:8]: one uint4 per segment.
// R9: k_node was the hidden ~95us: 64 blocks x 1 wave (25% of CUs, no TLP),
//  ~870-FMA serial chains per thread + global weight re-reads. Now 4 lanes
//  per node (one per edge dir), 16 nodes per 64-thr block -> 256 blocks;
//  weights staged to 1.7 KB LDS; agg via 2 shfl_xor.
// R5/R2 lessons: no launch-bounds below live set; constant-indexed reg arrays.
// MFMA layouts (HW-verified): A[m=lane&15][k=quad*8+j]; B[k=quad*8+j][n=lane&15];
// C/D col(n)=lane&15, row(m)=quad*4+reg.
// ---------------------------------------------------------------------------

typedef __attribute__((ext_vector_type(8))) short short8;
typedef __attribute__((ext_vector_type(4))) float f32x4;

#define ZROW  324                    // always-zero x1 row (rows 0..323 = 18x18)
#define NWTB  (12 * 4 * 48 * 8)      // 18432 shorts: B image [grp][quad][co:48][j:8]
#define ND1W  (256 * 48 * 8)         // 98304 shorts: dense1 bf16 [pixel][co:48][k:8]

static __device__ __forceinline__ unsigned short f2bf(float x) {
    unsigned int u = __float_as_uint(x);
    u += 0x7FFF + ((u >> 16) & 1);
    return (unsigned short)(u >> 16);
}

static __device__ __forceinline__ float diff_round(float x) {
    const float TP = 6.2831853071795864769f;
    return x - sinf(x * TP) / TP;
}

template<int IN, int OUT>
static __device__ __forceinline__ void mlp_layer(const float* in,
                                                 const float* __restrict__ w,
                                                 const float* __restrict__ b,
                                                 float* out, bool do_relu) {
#pragma unroll
    for (int j = 0; j < OUT; ++j) {
        float a = b[j];
#pragma unroll
        for (int i = 0; i < IN; ++i) a = fmaf(in[i], w[i * OUT + j], a);
        out[j] = do_relu ? fmaxf(a, 0.f) : a;
    }
}

// ---------------------------------------------------------------------------
// Prep: (a) wTbG = B-weight image in EXACTLY the k_patch LDS layout:
//   idx = ((grp*4+quad)*48 + co)*8 + j
//   grp<9 : tap=grp,      ci=quad*8+j   (main K-step, ci 0..31)
//   grp>=9: tap=(grp-9)*4+quad, ci=32+j (tail-packed K-step; tap>=9 -> 0)
// (b) d1wb = dense1 weights bf16, [pixel][co:48][k:8] (k>=6 or co>=40 -> 0).
// ---------------------------------------------------------------------------
__global__ __launch_bounds__(256) void k_prep(const float* __restrict__ w2,
                                              const float* __restrict__ d1w,
                                              unsigned short* __restrict__ wTbG,
                                              unsigned short* __restrict__ d1wb) {
    const int i = blockIdx.x * 256 + threadIdx.x;
    if (i < NWTB) {
        const int j    = i & 7;
        const int co   = (i >> 3) % 48;
        const int qg   = (i >> 3) / 48;
        const int quad = qg & 3;
        const int grp  = qg >> 2;
        float val = 0.f;
        if (grp < 9) {
            if (co < 40) val = w2[(grp * 40 + quad * 8 + j) * 40 + co];
        } else {
            const int tap = (grp - 9) * 4 + quad;
            if (tap < 9 && co < 40) val = w2[(tap * 40 + 32 + j) * 40 + co];
        }
        wTbG[i] = f2bf(val);
    } else if (i < NWTB + ND1W) {
        const int jj = i - NWTB;
        const int k  = jj & 7;
        const int co = (jj >> 3) % 48;
        const int px = (jj >> 3) / 48;
        d1wb[jj] = f2bf((co < 40 && k < 6) ? d1w[(px * 40 + co) * 6 + k] : 0.f);
    }
}

// ---------------------------------------------------------------------------
// Kernel 1: 512 threads/block, one block per patch.
// ph = t>>8 (conv1 channel half), pix = t&255, u=pix>>4, v=pix&15.
// Wave wv (0..7) owns pixel rows wv*2, wv*2+1 in the MFMA phase.
// ---------------------------------------------------------------------------
__global__ __launch_bounds__(512, 4) void k_patch(
    const float* __restrict__ img, const float* __restrict__ lab,
    const float* __restrict__ msk,
    const float* __restrict__ w1, const float* __restrict__ b1,
    const unsigned short* __restrict__ wTbG,
    const float* __restrict__ b2,
    const unsigned short* __restrict__ d1wb, const float* __restrict__ d1b,
    float* __restrict__ nodes, float* __restrict__ lsv)
{
    __shared__ __align__(16) unsigned short x1[325 * 40];   // 26,000 B
    __shared__ __align__(16) unsigned short Bs[NWTB];       // 36,864 B
    __shared__ float p[256];
    __shared__ float red[4][2];
    __shared__ float wsum[8][6];

    const int n = blockIdx.x;
    const int t = threadIdx.x;
    const int g = n >> 10, cell = n & 1023;
    const int gi = cell >> 5, gj = cell & 31;
    const int sx = g & 1, sy = g >> 1;           // SHIFTS (0,0),(1,0),(0,1),(1,1)
    const int gx = sx + 2 * gi, gy = sy + 2 * gj;
    const int px0 = gx * 8 - 4, py0 = gy * 8 - 4;
    const float cid = (float)(gx * 64 + gy);

    const int ph = t >> 8, pix = t & 255;
    const int u = pix >> 4, v = pix & 15;
    const int lane = t & 63, wv = t >> 6;
    const int lane15 = t & 15, quad = (t >> 4) & 3;

    // ---- entry: issue patch global loads (ph==0 half) ----
    float m = -1.f, iv = 0.f, lv = 0.f;
    if (ph == 0) {
        const int r = px0 + u, c = py0 + v;
        if (r >= 0 && r < 512 && c >= 0 && c < 512) {
            m  = msk[r * 512 + c];
            iv = img[r * 512 + c];
            lv = lab[r * 512 + c];
        }
    }

    // ---- stage B-weights into LDS (flat copy, layout matches exactly) ----
    {
        const uint4* src = (const uint4*)wTbG;
        uint4* dst = (uint4*)Bs;
        for (int i = t; i < NWTB / 8; i += 512) dst[i] = src[i];
    }

    // ---- zero x1 borders + ZROW (69 cells * 20 dwords) ----
    {
        unsigned int* x1w = (unsigned int*)x1;
        for (int i = t; i < 69 * 20; i += 512) {
            const int cellI = i / 20, d = i - cellI * 20;
            int cr;
            if      (cellI < 18) cr = cellI;                    // row 0
            else if (cellI < 36) cr = cellI + 288;              // row 17
            else if (cellI < 52) cr = (cellI - 35) * 18;        // col 0, rows 1..16
            else if (cellI < 68) cr = (cellI - 51) * 18 + 17;   // col 17
            else                 cr = ZROW;
            x1w[cr * 20 + d] = 0u;
        }
    }

    // ---- token + label stats (ph==0 waves) ----
    const float f = (m == cid) ? 1.f : 0.f;
    if (ph == 0) {
        p[pix] = iv * f;
        float sf = f, slf = lv * f;
        for (int off = 32; off; off >>= 1) {
            sf  += __shfl_down(sf,  off);
            slf += __shfl_down(slf, off);
        }
        if (lane == 0) { red[wv][0] = sf; red[wv][1] = slf; }
    }
    __syncthreads();                                   // B1

    if (t == 0) {
        const float SF = red[0][0] + red[1][0] + red[2][0] + red[3][0];
        const float SL = red[0][1] + red[1][1] + red[2][1] + red[3][1];
        lsv[n] = diff_round(diff_round(SL / (SF + 1e-8f)));
    }

    // ---- conv1: each thread: its pixel x its 20-channel half ----
    {
        float nbv[9];
#pragma unroll
        for (int ky = 0; ky < 3; ++ky)
#pragma unroll
            for (int kx = 0; kx < 3; ++kx) {
                const int uy = u + ky - 1, vx = v + kx - 1;
                const bool ok = (uy >= 0) && (uy < 16) && (vx >= 0) && (vx < 16);
                nbv[ky * 3 + kx] = ok ? p[uy * 16 + vx] : 0.f;
            }
        float a1[20];
#pragma unroll
        for (int cc = 0; cc < 20; ++cc) a1[cc] = b1[ph * 20 + cc];
#pragma unroll
        for (int k = 0; k < 9; ++k) {
            const float xv = nbv[k];
#pragma unroll
            for (int cc = 0; cc < 20; ++cc)
                a1[cc] = fmaf(xv, w1[k * 40 + ph * 20 + cc], a1[cc]);
        }
        const int row = (u + 1) * 18 + (v + 1);
        unsigned int* x1w = (unsigned int*)x1;
#pragma unroll
        for (int cg = 0; cg < 10; ++cg) {
            const unsigned int lo = f2bf(fmaxf(a1[2 * cg], 0.f));
            const unsigned int hi = f2bf(fmaxf(a1[2 * cg + 1], 0.f));
            x1w[row * 20 + ph * 10 + cg] = lo | (hi << 16);
        }
    }
    __syncthreads();                                   // B2: x1 + Bs ready

    // ---- conv2: 9 main + 3 tail-packed K-steps, all operands from LDS ----
    float bias[3];
#pragma unroll
    for (int nt = 0; nt < 3; ++nt) {
        const int co = nt * 16 + lane15;
        bias[nt] = (co < 40) ? b2[co] : 0.f;
    }
    f32x4 acc[2][3];
#pragma unroll
    for (int mt = 0; mt < 2; ++mt)
#pragma unroll
        for (int nt = 0; nt < 3; ++nt) {
            acc[mt][nt][0] = bias[nt]; acc[mt][nt][1] = bias[nt];
            acc[mt][nt][2] = bias[nt]; acc[mt][nt][3] = bias[nt];
        }

#pragma unroll
    for (int tap = 0; tap < 9; ++tap) {
        const int ky = tap / 3, kx = tap % 3;
        short8 bf[3];
#pragma unroll
        for (int nt = 0; nt < 3; ++nt)
            bf[nt] = *(const short8*)(Bs + ((tap * 4 + quad) * 48 + nt * 16 + lane15) * 8);
#pragma unroll
        for (int mt = 0; mt < 2; ++mt) {
            const int arow = (wv * 2 + mt + ky) * 18 + (lane15 + kx);
            const short8 a0 = *(const short8*)(x1 + arow * 40 + quad * 8);
#pragma unroll
            for (int nt = 0; nt < 3; ++nt)
                acc[mt][nt] = __builtin_amdgcn_mfma_f32_16x16x32_bf16(
                    a0, bf[nt], acc[mt][nt], 0, 0, 0);
        }
    }
#pragma unroll
    for (int s = 0; s < 3; ++s) {
        short8 bt[3];
#pragma unroll
        for (int nt = 0; nt < 3; ++nt)
            bt[nt] = *(const short8*)(Bs + (((9 + s) * 4 + quad) * 48 + nt * 16 + lane15) * 8);
        const int tapq = s * 4 + quad;
        const int kyq  = (tapq * 11) >> 5;             // tapq/3 for 0..11
        const int kxq  = tapq - 3 * kyq;
#pragma unroll
        for (int mt = 0; mt < 2; ++mt) {
            const int arowq = (wv * 2 + mt + kyq) * 18 + (lane15 + kxq);
            const int offs  = (tapq < 9) ? (arowq * 40 + 32) : (ZROW * 40);
            const short8 at = *(const short8*)(x1 + offs);
#pragma unroll
            for (int nt = 0; nt < 3; ++nt)
                acc[mt][nt] = __builtin_amdgcn_mfma_f32_16x16x32_bf16(
                    at, bt[nt], acc[mt][nt], 0, 0, 0);
        }
    }

    // ---- dense1 straight from accumulators; bf16 weights, 1 uint4/segment --
    float a6[6] = {0.f, 0.f, 0.f, 0.f, 0.f, 0.f};
#pragma unroll
    for (int mt = 0; mt < 2; ++mt)
#pragma unroll
        for (int nt = 0; nt < 3; ++nt) {
            const int co = nt * 16 + lane15;
#pragma unroll
            for (int reg = 0; reg < 4; ++reg) {
                const int pixel = (wv * 2 + mt) * 16 + quad * 4 + reg;
                const uint4 wq = *(const uint4*)(d1wb + ((pixel * 48 + co) << 3));
                const float a = fmaxf(acc[mt][nt][reg], 0.f);
                a6[0] = fmaf(a, __uint_as_float(wq.x << 16),          a6[0]);
                a6[1] = fmaf(a, __uint_as_float(wq.x & 0xFFFF0000u),  a6[1]);
                a6[2] = fmaf(a, __uint_as_float(wq.y << 16),          a6[2]);
                a6[3] = fmaf(a, __uint_as_float(wq.y & 0xFFFF0000u),  a6[3]);
                a6[4] = fmaf(a, __uint_as_float(wq.z << 16),          a6[4]);
                a6[5] = fmaf(a, __uint_as_float(wq.z & 0xFFFF0000u),  a6[5]);
            }
        }
    for (int off = 32; off; off >>= 1) {
#pragma unroll
        for (int k = 0; k < 6; ++k) a6[k] += __shfl_down(a6[k], off);
    }
    if (lane == 0) {
#pragma unroll
        for (int k = 0; k < 6; ++k) wsum[wv][k] = a6[k];
    }
    __syncthreads();                                   // B3
    if (t < 6) {
        float s = d1b[t];
#pragma unroll
        for (int w = 0; w < 8; ++w) s += wsum[w][t];
        nodes[n * 6 + t] = fmaxf(s, 0.f);
    }
}

// ---------------------------------------------------------------------------
// Kernel 2 (R9): 4 lanes per node (one per edge direction), 16 nodes per
// 64-thread block -> 256 blocks (full CU coverage vs 64 before).
// All MLP weights staged once into 1.7 KB LDS (uniform-address broadcast
// reads, no global re-loads, no register-pressure spills).
// agg = segment_sum over <=4 incoming edges = 2x shfl_xor in the 4-lane group.
// node_id(x,y) = ((x&1)+2*(y&1))*1024 + (x>>1)*32 + (y>>1).
// ---------------------------------------------------------------------------

// LDS weight-pool offsets (floats)
#define OWE0 0      // 65 = 13*5
#define OBE0 65     // 5
#define OWE1 70     // 25
#define OBE1 95     // 5
#define OWE2 100    // 25
#define OBE2 125    // 5
#define OWE3 130    // 50 = 5*10
#define OBE3 180    // 10
#define OWN0 190    // 85 = 17*5
#define OBN0 275    // 5
#define OWN1 280    // 25
#define OBN1 305    // 5
#define OWN2 310    // 25
#define OBN2 335    // 5
#define OWN3 340    // 50
#define OBN3 390    // 10
#define OWOUT 400   // 20
#define OBOUT 420   // 2
#define NWPOOL 422

__global__ __launch_bounds__(64) void k_node(
    const float* __restrict__ nodes, const float* __restrict__ lsv,
    const float* __restrict__ we0, const float* __restrict__ be0,
    const float* __restrict__ we1, const float* __restrict__ be1,
    const float* __restrict__ we2, const float* __restrict__ be2,
    const float* __restrict__ we3, const float* __restrict__ be3,
    const float* __restrict__ wn0, const float* __restrict__ bn0,
    const float* __restrict__ wn1, const float* __restrict__ bn1,
    const float* __restrict__ wn2, const float* __restrict__ bn2,
    const float* __restrict__ wn3, const float* __restrict__ bn3,
    const float* __restrict__ wout, const float* __restrict__ bout,
    float* __restrict__ out, int N)
{
    __shared__ float L[NWPOOL];
    const int t = threadIdx.x;

    // ---- stage all weights to LDS (once per block) ----
    {
        const float* srcs[18] = {we0, be0, we1, be1, we2, be2, we3, be3,
                                 wn0, bn0, wn1, bn1, wn2, bn2, wn3, bn3,
                                 wout, bout};
        const int lens[18] = {65, 5, 25, 5, 25, 5, 50, 10,
                              85, 5, 25, 5, 25, 5, 50, 10, 20, 2};
        int off = 0;
        for (int a = 0; a < 18; ++a) {
            for (int i = t; i < lens[a]; i += 64) L[off + i] = srcs[a][i];
            off += lens[a];
        }
    }
    __syncthreads();

    const int n = blockIdx.x * 16 + (t >> 2);    // node id
    const int d = t & 3;                         // edge direction lane
    const bool nvalid = n < N;

    const int g = n >> 10, cell = n & 1023;
    const int gi = cell >> 5, gj = cell & 31;
    const int gx = (g & 1) + 2 * gi, gy = (g >> 1) + 2 * gj;

    float self6[6];
#pragma unroll
    for (int i = 0; i < 6; ++i) self6[i] = nvalid ? nodes[n * 6 + i] : 0.f;

    // ---- one edge MLP per lane ----
    const int DX[4] = {0, 0, -1, 1};
    const int DY[4] = {-1, 1, 0, 0};
    const int x = gx + DX[d], y = gy + DY[d];
    const bool ev = nvalid && x >= 0 && x < 64 && y >= 0 && y < 64;

    float o10[10];
#pragma unroll
    for (int j = 0; j < 10; ++j) o10[j] = 0.f;
    if (ev) {
        const int mid = ((x & 1) + 2 * (y & 1)) * 1024 + (x >> 1) * 32 + (y >> 1);
        float in13[13];
#pragma unroll
        for (int i = 0; i < 6; ++i) in13[i] = nodes[mid * 6 + i];
#pragma unroll
        for (int i = 0; i < 6; ++i) in13[6 + i] = self6[i];
        in13[12] = 1.f;
        float h0[5], h1[5], h2[5];
        mlp_layer<13, 5>(in13, L + OWE0, L + OBE0, h0, true);
        mlp_layer<5, 5>(h0, L + OWE1, L + OBE1, h1, true);
        mlp_layer<5, 5>(h1, L + OWE2, L + OBE2, h2, true);
        mlp_layer<5, 10>(h2, L + OWE3, L + OBE3, o10, false);
    }

    // ---- segment_sum over the 4-lane group (aligned: lanes 4k..4k+3) ----
    float agg[10];
#pragma unroll
    for (int j = 0; j < 10; ++j) {
        float v = o10[j];
        v += __shfl_xor(v, 1);
        v += __shfl_xor(v, 2);
        agg[j] = v;
    }

    // ---- node MLP (all 4 lanes compute redundantly; lane d==0 writes) ----
    float in17[17];
#pragma unroll
    for (int i = 0; i < 6; ++i)  in17[i]     = self6[i];
#pragma unroll
    for (int i = 0; i < 10; ++i) in17[6 + i] = agg[i];
    in17[16] = 1.f;
    float h0[5], h1[5], h2[5], o[10];
    mlp_layer<17, 5>(in17, L + OWN0, L + OBN0, h0, true);
    mlp_layer<5, 5>(h0, L + OWN1, L + OBN1, h1, true);
    mlp_layer<5, 5>(h1, L + OWN2, L + OBN2, h2, true);
    mlp_layer<5, 10>(h2, L + OWN3, L + OBN3, o, false);

    float l0 = L[OBOUT + 0], l1 = L[OBOUT + 1];
#pragma unroll
    for (int i = 0; i < 10; ++i) {
        l0 = fmaf(o[i], L[OWOUT + i * 2 + 0], l0);
        l1 = fmaf(o[i], L[OWOUT + i * 2 + 1], l1);
    }
    if (d == 0 && nvalid) {
        const float mx  = fmaxf(l0, l1);
        const float e0  = expf(l0 - mx), e1 = expf(l1 - mx);
        const float lse = mx + logf(e0 + e1);
        const float sv  = lsv[n];
        out[n] = -((1.f - sv) * (l0 - lse) + sv * (l1 - lse));
    }
}

// ---------------------------------------------------------------------------
extern "C" void kernel_launch(void* const* d_in, const int* in_sizes, int n_in,
                              void* d_out, int out_size, void* d_ws, size_t ws_size,
                              hipStream_t stream) {
    (void)n_in; (void)ws_size; (void)in_sizes;
    const float* img = (const float*)d_in[0];
    const float* lab = (const float*)d_in[1];
    const float* msk = (const float*)d_in[2];
    const float* w1  = (const float*)d_in[3];
    const float* b1  = (const float*)d_in[4];
    const float* w2  = (const float*)d_in[5];
    const float* b2  = (const float*)d_in[6];
    const float* d1w = (const float*)d_in[7];
    const float* d1b = (const float*)d_in[8];
    const float* we0 = (const float*)d_in[9],  *be0 = (const float*)d_in[10];
    const float* we1 = (const float*)d_in[11], *be1 = (const float*)d_in[12];
    const float* we2 = (const float*)d_in[13], *be2 = (const float*)d_in[14];
    const float* we3 = (const float*)d_in[15], *be3 = (const float*)d_in[16];
    const float* wn0 = (const float*)d_in[17], *bn0 = (const float*)d_in[18];
    const float* wn1 = (const float*)d_in[19], *bn1 = (const float*)d_in[20];
    const float* wn2 = (const float*)d_in[21], *bn2 = (const float*)d_in[22];
    const float* wn3 = (const float*)d_in[23], *bn3 = (const float*)d_in[24];
    const float* wout = (const float*)d_in[25], *bout = (const float*)d_in[26];
    const int N = out_size;              // 4096 nodes

    char* base = (char*)d_ws;
    float* nodes = (float*)base;                             // N*6 floats
    float* lsvb  = (float*)(base + (size_t)N * 6 * 4);       // N floats
    unsigned short* wTbG = (unsigned short*)(base + (size_t)N * 7 * 4);  // 18432
    unsigned short* d1wb = wTbG + NWTB;                      // 98304
    float* out   = (float*)d_out;

    const int prep_n = NWTB + ND1W;
    k_prep<<<(prep_n + 255) / 256, 256, 0, stream>>>(w2, d1w, wTbG, d1wb);
    k_patch<<<N, 512, 0, stream>>>(img, lab, msk, w1, b1, wTbG, b2,
                                   d1wb, d1b, nodes, lsvb);
    k_node<<<(N + 15) / 16, 64, 0, stream>>>(nodes, lsvb,
                                             we0, be0, we1, be1, we2, be2,
                                             we3, be3,
                                             wn0, bn0, wn1, bn1, wn2, bn2,
                                             wn3, bn3, wout, bout, out, N);
}